// Round 14
// baseline (334.994 us; speedup 1.0000x reference)
//
#include <hip/hip_runtime.h>
#include <stdint.h>

#define B_   16
#define N_   4096
#define M_   1024
#define C1_  256
#define C2_  512
#define H_   256
#define K1_  768      // C1+C2
#define P_   65536    // B*N

typedef unsigned int  uint_t;
typedef unsigned short ushort_t;
typedef __attribute__((ext_vector_type(4))) float f32x4;
typedef __attribute__((ext_vector_type(8))) short s16x8;

__device__ __forceinline__ float b2f(ushort_t u) {
    union { uint_t i; float f; } v; v.i = ((uint_t)u) << 16; return v.f;
}
__device__ __forceinline__ ushort_t f2b(float f) {
    union { float f; uint_t i; } v; v.f = f;
    uint_t x = v.i;
    return (ushort_t)((x + 0x7fffu + ((x >> 16) & 1u)) >> 16);  // RNE
}

__device__ __forceinline__ void async16(const void* g, void* l) {
    __builtin_amdgcn_global_load_lds(
        (const __attribute__((address_space(1))) uint_t*)g,
        (__attribute__((address_space(3))) uint_t*)l, 16, 0, 0);
}

// ---------------------------------------------------------------------------
// initw_k: blocks 0..1023 convert w1/w2 to bf16; block 1024 zeroes the
// shadow-stat arrays (9216 f32) and the two gemm completion counters.
// ---------------------------------------------------------------------------
__global__ __launch_bounds__(256) void initw_k(
    const float* __restrict__ w1, const float* __restrict__ w2,
    ushort_t* __restrict__ w1b, ushort_t* __restrict__ w2b,
    float* __restrict__ fb, uint_t* __restrict__ cnts) {
    int blk = blockIdx.x;
    if (blk < 1024) {
        int t = blk * 256 + threadIdx.x;   // 262144 total
        if (t < H_ * K1_) w1b[t] = f2b(w1[t]);
        else { int u = t - H_ * K1_; w2b[u] = f2b(w2[u]); }
    } else {
        for (int i = threadIdx.x; i < 9216; i += 256) fb[i] = 0.0f;
        if (threadIdx.x < 2) cnts[threadIdx.x] = 0u;
    }
}

// ---------------------------------------------------------------------------
// trans_k: LDS-FREE vectorized transposes (was 64-insts-per-16-elems via
// LDS tiles at 27% HBM; now 8 coalesced dword reads + 1 dwordx4 store per
// 8 outputs). Per-lane output stride = row pitch, but each block fills 64
// consecutive rows completely -> L2 write-combines to full lines.
//  blocks [0,512):     kf (B,512,1024) f32 -> kfT (B,1024,512) bf16
//                      (b = bid>>5, m-tile of 64, c-half of 256)
//  blocks [512,1536):  uf (B,256,4096) f32 -> Acat (P,768) bf16 cols 0..255
//                      (b = id>>6, n-tile of 64)
// All 1536 blocks move ~96 KB. Same f2b RNE -> bit-identical values.
// ---------------------------------------------------------------------------
__global__ __launch_bounds__(256) void trans_k(
    const float* __restrict__ kf, ushort_t* __restrict__ kfT,
    const float* __restrict__ uf, ushort_t* __restrict__ Acat) {
    int bid = blockIdx.x;
    int t = threadIdx.x;
    int lane = t & 63;            // point within tile
    int ch = t >> 6;              // chunk-group 0..3
    if (bid < 512) {
        int b = bid >> 5;                    // batch
        int m0 = ((bid >> 1) & 15) * 64;     // m-tile
        int cb = (bid & 1) * 256;            // channel half
        const float* src = kf + (size_t)b * C2_ * M_ + m0 + lane;
        ushort_t* dst = kfT + ((size_t)b * M_ + m0 + lane) * C2_;
#pragma unroll 2
        for (int pass = 0; pass < 8; ++pass) {
            int c = cb + (pass * 4 + ch) * 8;
            float v[8];
#pragma unroll
            for (int j = 0; j < 8; ++j)
                v[j] = src[(size_t)(c + j) * M_];
            uint4 pk;
            pk.x = (uint_t)f2b(v[0]) | ((uint_t)f2b(v[1]) << 16);
            pk.y = (uint_t)f2b(v[2]) | ((uint_t)f2b(v[3]) << 16);
            pk.z = (uint_t)f2b(v[4]) | ((uint_t)f2b(v[5]) << 16);
            pk.w = (uint_t)f2b(v[6]) | ((uint_t)f2b(v[7]) << 16);
            *(uint4*)(dst + c) = pk;
        }
    } else {
        int id = bid - 512;                  // 0..1023
        int b = id >> 6;                     // batch
        int n0 = (id & 63) * 64;             // n-tile
        const float* src = uf + (size_t)b * C1_ * N_ + n0 + lane;
        ushort_t* dst = Acat + ((size_t)b * N_ + n0 + lane) * K1_;
#pragma unroll 2
        for (int pass = 0; pass < 8; ++pass) {
            int c = (pass * 4 + ch) * 8;
            float v[8];
#pragma unroll
            for (int j = 0; j < 8; ++j)
                v[j] = src[(size_t)(c + j) * N_];
            uint4 pk;
            pk.x = (uint_t)f2b(v[0]) | ((uint_t)f2b(v[1]) << 16);
            pk.y = (uint_t)f2b(v[2]) | ((uint_t)f2b(v[3]) << 16);
            pk.z = (uint_t)f2b(v[4]) | ((uint_t)f2b(v[5]) << 16);
            pk.w = (uint_t)f2b(v[6]) | ((uint_t)f2b(v[7]) << 16);
            *(uint4*)(dst + c) = pk;
        }
    }
}

// ---------------------------------------------------------------------------
// FUSED 3-NN + weighted gather (round-12 structure: med3-insk, barrier-free
// reg handoff, bijective XCD swizzle). NEW: weights in f32 (4 f32 divides
// vs 4 fp64 — weights already carry ~2e-4 relative from the 12-bit key
// truncation, tolerated since round 4; f32 adds ~1e-7).
// ---------------------------------------------------------------------------
__device__ __forceinline__ uint_t umin_(uint_t a, uint_t b) { return a < b ? a : b; }
__device__ __forceinline__ uint_t umax_(uint_t a, uint_t b) { return a > b ? a : b; }

__device__ __forceinline__ uint_t med3u(uint_t a, uint_t b, uint_t c) {
    uint_t d;
    asm("v_med3_u32 %0, %1, %2, %3" : "=v"(d) : "v"(a), "v"(b), "v"(c));
    return d;
}

// sorted insert keeping 4 smallest: new k_i = med3(key, k_{i-1}, k_i)
__device__ __forceinline__ void insk(uint_t key,
        uint_t& k0, uint_t& k1, uint_t& k2, uint_t& k3) {
    uint_t n3 = med3u(key, k2, k3);
    uint_t n2 = med3u(key, k1, k2);
    uint_t n1 = med3u(key, k0, k1);
    k0 = umin_(k0, key);
    k1 = n1; k2 = n2; k3 = n3;
}

// merge partner's sorted quad (via shfl_xor) with mine: bitonic lowest-4.
__device__ __forceinline__ void mrg4(int off,
        uint_t& a0, uint_t& a1, uint_t& a2, uint_t& a3) {
    uint_t e0 = (uint_t)__shfl_xor((int)a0, off);
    uint_t e1 = (uint_t)__shfl_xor((int)a1, off);
    uint_t e2 = (uint_t)__shfl_xor((int)a2, off);
    uint_t e3 = (uint_t)__shfl_xor((int)a3, off);
    uint_t c0 = umin_(a0, e3), c1 = umin_(a1, e2);
    uint_t c2 = umin_(a2, e1), c3 = umin_(a3, e0);   // bitonic, holds 4 smallest
    uint_t l0 = umin_(c0, c2), h0 = umax_(c0, c2);
    uint_t l1 = umin_(c1, c3), h1 = umax_(c1, c3);
    a0 = umin_(l0, l1); a1 = umax_(l0, l1);
    a2 = umin_(h0, h1); a3 = umax_(h0, h1);
}

__device__ __forceinline__ void ins3d(double d, int m,
                                      double& d0, int& i0, double& d1, int& i1,
                                      double& d2, int& i2) {
    if (d < d2 || (d == d2 && m < i2)) {
        d2 = d; i2 = m;
        if (d2 < d1 || (d2 == d1 && i2 < i1)) { double td = d1; d1 = d2; d2 = td; int ti = i1; i1 = i2; i2 = ti; }
        if (d1 < d0 || (d1 == d0 && i1 < i0)) { double td = d0; d0 = d1; d1 = td; int ti = i0; i0 = i1; i1 = ti; }
    }
}

__global__ __launch_bounds__(256) void knn_k(
    const float* __restrict__ unknown, const float* __restrict__ known,
    const ushort_t* __restrict__ kfT, ushort_t* __restrict__ Acat) {
    __shared__ float4 kpt[M_];             // (x, y, z, |k|^2 fp32) — 16 KB
    // bijective XCD swizzle (2048 % 8 == 0): XCD x serves batches {2x, 2x+1}
    int blk = ((blockIdx.x & 7) << 8) | (blockIdx.x >> 3);
    int b = blk >> 7;                      // batch
    int n0 = (blk & 127) * 32;             // 32 queries per block
    int t = threadIdx.x;
    int qg = t >> 4;                       // query pair 0..15
    int sub = t & 15;                      // candidate slice 0..15

    for (int m = t; m < M_; m += 256) {
        float x = known[((size_t)b * M_ + m) * 3 + 0];
        float y = known[((size_t)b * M_ + m) * 3 + 1];
        float z = known[((size_t)b * M_ + m) * 3 + 2];
        kpt[m] = make_float4(x, y, z, x * x + y * y + z * z);
    }
    __syncthreads();

    int n = n0 + qg * 2;
    float qx0 = unknown[((size_t)b * N_ + n) * 3 + 0];
    float qy0 = unknown[((size_t)b * N_ + n) * 3 + 1];
    float qz0 = unknown[((size_t)b * N_ + n) * 3 + 2];
    float qx1 = unknown[((size_t)b * N_ + n + 1) * 3 + 0];
    float qy1 = unknown[((size_t)b * N_ + n + 1) * 3 + 1];
    float qz1 = unknown[((size_t)b * N_ + n + 1) * 3 + 2];
    float qs0 = qx0 * qx0 + qy0 * qy0 + qz0 * qz0;
    float qs1 = qx1 * qx1 + qy1 * qy1 + qz1 * qz1;

    const uint_t DMASK = 0xFFFFFC00u;
    uint_t A0 = 0xFFFFFFFFu, A1 = 0xFFFFFFFFu, A2 = 0xFFFFFFFFu, A3 = 0xFFFFFFFFu;
    uint_t B0 = 0xFFFFFFFFu, B1 = 0xFFFFFFFFu, B2 = 0xFFFFFFFFu, B3 = 0xFFFFFFFFu;

#pragma unroll 4
    for (int j = 0; j < 64; ++j) {
        int m = j * 16 + sub;
        float4 kp = kpt[m];
        float dot0 = fmaf(qx0, kp.x, fmaf(qy0, kp.y, qz0 * kp.z));
        float d0 = fmaxf(fmaf(-2.0f, dot0, qs0 + kp.w), 0.0f);
        uint_t k0 = (__float_as_uint(d0) & DMASK) | (uint_t)m;
        insk(k0, A0, A1, A2, A3);
        float dot1 = fmaf(qx1, kp.x, fmaf(qy1, kp.y, qz1 * kp.z));
        float d1 = fmaxf(fmaf(-2.0f, dot1, qs1 + kp.w), 0.0f);
        uint_t k1 = (__float_as_uint(d1) & DMASK) | (uint_t)m;
        insk(k1, B0, B1, B2, B3);
    }

    // merge across the 16 subs (lane bits 0..3)
#pragma unroll
    for (int off = 1; off < 16; off <<= 1) {
        mrg4(off, A0, A1, A2, A3);
        mrg4(off, B0, B1, B2, B3);
    }
    // all 16 subs of a query pair now hold the same top-4 keys

    int   F0r[2], F1r[2], F2r[2];
    float wxr[2], wyr[2], wzr[2];
#pragma unroll
    for (int qi = 0; qi < 2; ++qi) {
        uint_t K0 = qi ? B0 : A0, K1 = qi ? B1 : A1;
        uint_t K2 = qi ? B2 : A2, K3 = qi ? B3 : A3;
        float qx = qi ? qx1 : qx0, qy = qi ? qy1 : qy0;
        float qz = qi ? qz1 : qz0, qs = qi ? qs1 : qs0;

        float d0t = __uint_as_float(K0 & DMASK);
        float d1t = __uint_as_float(K1 & DMASK);
        float d2t = __uint_as_float(K2 & DMASK);
        float d3t = __uint_as_float(K3 & DMASK);
        float margin = fmaf(d3t, 2.5e-4f, 4.0e-5f);
        bool flagged = (d3t - d2t) <= margin;

        float e0, e1, e2; int F0, F1, F2;
        if (!flagged) {
            e0 = d0t; e1 = d1t; e2 = d2t;
            F0 = (int)(K0 & 0x3FFu);
            F1 = (int)(K1 & 0x3FFu);
            F2 = (int)(K2 & 0x3FFu);
        } else {
            // exact fallback: fp32 rescan + fp64 lexicographic insert for
            // candidates that can possibly be in the true top-3.
            float fthr = d2t + margin;
            double qdx = (double)qx, qdy = (double)qy, qdz = (double)qz;
            double qds = qdx * qdx + qdy * qdy + qdz * qdz;
            double Z0 = 1e300, Z1 = 1e300, Z2 = 1e300;
            int    G0 = 0x7fffffff, G1 = 0x7fffffff, G2 = 0x7fffffff;
            for (int m = sub; m < M_; m += 16) {
                float4 kp = kpt[m];
                float dot = fmaf(qx, kp.x, fmaf(qy, kp.y, qz * kp.z));
                float df = fmaf(-2.0f, dot, qs + kp.w);
                if (df <= fthr) {
                    double X = (double)kp.x, Y = (double)kp.y, Z = (double)kp.z;
                    double ks = X * X + Y * Y + Z * Z;      // same order as fp64 ref
                    double dd = qdx * X + qdy * Y + qdz * Z;
                    double de = qds + ks - 2.0 * dd;
                    ins3d(de, m, Z0, G0, Z1, G1, Z2, G2);
                }
            }
#pragma unroll
            for (int off = 1; off < 16; off <<= 1) {
                double f0 = __shfl_xor(Z0, off), f1 = __shfl_xor(Z1, off), f2 = __shfl_xor(Z2, off);
                int    j0 = __shfl_xor(G0, off), j1 = __shfl_xor(G1, off), j2 = __shfl_xor(G2, off);
                ins3d(f0, j0, Z0, G0, Z1, G1, Z2, G2);
                ins3d(f1, j1, Z0, G0, Z1, G1, Z2, G2);
                ins3d(f2, j2, Z0, G0, Z1, G1, Z2, G2);
            }
            e0 = (float)Z0; e1 = (float)Z1; e2 = (float)Z2;
            F0 = G0; F1 = G1; F2 = G2;
        }

        float w0 = 1.0f / (e0 + 1e-8f);
        float w1 = 1.0f / (e1 + 1e-8f);
        float w2 = 1.0f / (e2 + 1e-8f);
        float inv = 1.0f / (w0 + w1 + w2);
        F0r[qi] = F0; F1r[qi] = F1; F2r[qi] = F2;
        wxr[qi] = w0 * inv;
        wyr[qi] = w1 * inv;
        wzr[qi] = w2 * inv;
    }

    // ---- gather phase (no barrier): wave wid owns queries wid*8..wid*8+7;
    // idx/weights broadcast from lane p*16 via shfl (uniform in each group).
    {
        int lane = t & 63, wid = t >> 6;
        size_t pbase = (size_t)b * N_ + n0 + wid * 8;
        const ushort_t* kfb = kfT + (size_t)b * M_ * C2_;
#pragma unroll
        for (int p = 0; p < 4; ++p) {
#pragma unroll
            for (int qi = 0; qi < 2; ++qi) {
                int src = p << 4;
                int i0 = __shfl(F0r[qi], src);
                int i1 = __shfl(F1r[qi], src);
                int i2 = __shfl(F2r[qi], src);
                float wx = __shfl(wxr[qi], src);
                float wy = __shfl(wyr[qi], src);
                float wz = __shfl(wzr[qi], src);
                const uint4* r0 = (const uint4*)(kfb + (size_t)i0 * C2_);
                const uint4* r1 = (const uint4*)(kfb + (size_t)i1 * C2_);
                const uint4* r2 = (const uint4*)(kfb + (size_t)i2 * C2_);
                uint4 v0 = r0[lane], v1 = r1[lane], v2 = r2[lane];
                const ushort_t* p0 = (const ushort_t*)&v0;
                const ushort_t* p1 = (const ushort_t*)&v1;
                const ushort_t* p2 = (const ushort_t*)&v2;
                uint4 o; ushort_t* po = (ushort_t*)&o;
                for (int j = 0; j < 8; ++j) {
                    float f = wx * b2f(p0[j]) + wy * b2f(p1[j]) + wz * b2f(p2[j]);
                    po[j] = f2b(f);
                }
                ((uint4*)(Acat + (pbase + p * 2 + qi) * K1_ + C1_))[lane] = o;
            }
        }
    }
}

// ---------------------------------------------------------------------------
// Unified GEMM + fused column stats + LAST-BLOCK BN-coef computation.
// Pipeline: 3-buffer, depth 2, counted vmcnt + raw s_barrier. Stats: quad
// shfl-reduce -> LDS [2][256] -> block combine -> atomicAdd into 8 shadow
// copies -> last block folds shadows (coherent atomic-read path) and
// computes a/c with the exact coef arithmetic.
// ---------------------------------------------------------------------------
__global__ __launch_bounds__(512, 4) void gemm_k(
    const ushort_t* __restrict__ A, const ushort_t* __restrict__ Bw,
    ushort_t* __restrict__ C, int K,
    float* __restrict__ sumP, float* __restrict__ sqP,
    const float* __restrict__ g, const float* __restrict__ bt,
    float* __restrict__ a, float* __restrict__ c,
    uint_t* __restrict__ cnt) {
    __shared__ ushort_t As[3][128 * 32];
    __shared__ ushort_t Bs[3][256 * 32];
    __shared__ uint_t lastFlag;
    int t = threadIdx.x, lane = t & 63, wid = t >> 6;
    int wm = wid & 1, wn = wid >> 1;           // 2 x 4 wave grid -> 64x64 each
    int row0 = blockIdx.x * 128;
    int quad = lane >> 4, l15 = lane & 15;
    int srow = lane >> 2, kc = lane & 3;
    int kcs = kc ^ ((srow >> 1) & 3);          // swizzled source chunk
    int rsw = (l15 >> 1) & 3;                  // read-side swizzle key

    f32x4 acc[4][4] = {};

    auto stage = [&](int buf, int k0) {
        async16(A + ((size_t)(row0 + wid * 16 + srow)) * K + k0 + kcs * 8,
                &As[buf][wid * 16 * 32]);
#pragma unroll
        for (int j = 0; j < 2; ++j) {
            int rbase = wid * 32 + j * 16;
            async16(Bw + ((size_t)(rbase + srow)) * K + k0 + kcs * 8,
                    &Bs[buf][rbase * 32]);
        }
    };

    int nt = K >> 5;                 // 24 or 8
    stage(0, 0);
    stage(1, 32);

    int bi = 0;
    for (int it = 0; it < nt; ++it) {
        int pf = it + 2;
        if (pf < nt) stage(pf % 3, pf * 32);

        if (it < nt - 2)      asm volatile("s_waitcnt vmcnt(6)" ::: "memory");
        else if (it == nt - 2) asm volatile("s_waitcnt vmcnt(3)" ::: "memory");
        else                  asm volatile("s_waitcnt vmcnt(0)" ::: "memory");
        __builtin_amdgcn_s_barrier();          // all waves' tile-it loads landed
        asm volatile("" ::: "memory");

        s16x8 af[4], bfr[4];
#pragma unroll
        for (int i = 0; i < 4; ++i)
            af[i] = *(const s16x8*)&As[bi][(wm * 64 + i * 16 + l15) * 32 + ((quad ^ rsw) * 8)];
#pragma unroll
        for (int j = 0; j < 4; ++j)
            bfr[j] = *(const s16x8*)&Bs[bi][(wn * 64 + j * 16 + l15) * 32 + ((quad ^ rsw) * 8)];
#pragma unroll
        for (int i = 0; i < 4; ++i)
#pragma unroll
            for (int j = 0; j < 4; ++j)
                acc[i][j] = __builtin_amdgcn_mfma_f32_16x16x32_bf16(
                    af[i], bfr[j], acc[i][j], 0, 0, 0);

        asm volatile("" ::: "memory");
        __builtin_amdgcn_s_barrier();          // reads of buf bi done -> reusable
        asm volatile("" ::: "memory");
        bi = (bi + 1 == 3) ? 0 : bi + 1;
    }

    float colS[4] = {0.f, 0.f, 0.f, 0.f};
    float colQ[4] = {0.f, 0.f, 0.f, 0.f};
#pragma unroll
    for (int i = 0; i < 4; ++i)
#pragma unroll
        for (int j = 0; j < 4; ++j)
#pragma unroll
            for (int r = 0; r < 4; ++r) {
                int m = row0 + wm * 64 + i * 16 + quad * 4 + r;
                int nn = wn * 64 + j * 16 + l15;
                ushort_t cv = f2b(acc[i][j][r]);
                C[(size_t)m * H_ + nn] = cv;
                float v = b2f(cv);
                colS[j] += v;
                colQ[j] += v * v;
            }
    // reduce over quad (lane bits 4,5)
#pragma unroll
    for (int j = 0; j < 4; ++j) {
        colS[j] += __shfl_xor(colS[j], 16);
        colS[j] += __shfl_xor(colS[j], 32);
        colQ[j] += __shfl_xor(colQ[j], 16);
        colQ[j] += __shfl_xor(colQ[j], 32);
    }
    // block-level reduce via LDS (As is dead after the final barrier)
    float* ps = (float*)&As[0][0];   // [2][256]
    float* pq = ps + 512;            // [2][256]
    if (quad == 0) {
#pragma unroll
        for (int j = 0; j < 4; ++j) {
            int nn = wn * 64 + j * 16 + l15;
            ps[wm * 256 + nn] = colS[j];
            pq[wm * 256 + nn] = colQ[j];
        }
    }
    __syncthreads();
    if (t < 256) {
        float s = ps[t] + ps[256 + t];
        float q = pq[t] + pq[256 + t];
        int sh = (blockIdx.x & 7) * 256 + t;   // 8 shadow copies
        atomicAdd(&sumP[sh], s);
        atomicAdd(&sqP[sh], q);
    }
    // last-block BN-coef: syncthreads drains this block's atomics (vmcnt(0)
    // before s_barrier), so counter==gridDim implies all shadow adds landed.
    __syncthreads();
    if (t == 0)
        lastFlag = (atomicAdd(cnt, 1u) == (uint_t)(gridDim.x - 1)) ? 1u : 0u;
    __syncthreads();
    if (lastFlag != 0u && t < 256) {
        float s = 0.f, q = 0.f;
#pragma unroll
        for (int k = 0; k < 8; ++k) {
            s += atomicAdd(&sumP[k * 256 + t], 0.0f);   // coherent read path
            q += atomicAdd(&sqP[k * 256 + t], 0.0f);
        }
        float mean = s * (1.0f / P_);
        float var  = q * (1.0f / P_) - mean * mean;
        float ai = g[t] * rsqrtf(var + 1e-5f);
        a[t] = ai;
        c[t] = bt[t] - mean * ai;
    }
}

// BN + ReLU elementwise: x1 (P,256) bf16 -> h1 bf16, one uint4 (8 elems)/thread
__global__ __launch_bounds__(256) void bnrelu_k(
    const uint4* __restrict__ x, const float* __restrict__ a,
    const float* __restrict__ c, uint4* __restrict__ h) {
    size_t i = (size_t)blockIdx.x * 256 + threadIdx.x;   // 2,097,152 uint4s
    uint4 v = x[i];
    int chb = (int)((i * 8) & 255);
    const ushort_t* pv = (const ushort_t*)&v;
    uint4 o; ushort_t* po = (ushort_t*)&o;
    for (int j = 0; j < 8; ++j) {
        float f = b2f(pv[j]);
        f = a[chb + j] * f + c[chb + j];
        po[j] = f2b(fmaxf(f, 0.0f));
    }
    h[i] = o;
}

// BN + ReLU + transpose: x2 (P,256) bf16 -> out (B,256,N) f32, 64x64 tiles
__global__ __launch_bounds__(256) void final_k(
    const ushort_t* __restrict__ x2, const float* __restrict__ a,
    const float* __restrict__ c, float* __restrict__ out) {
    __shared__ float tile[64][65];
    int n0 = blockIdx.x * 64, c0 = blockIdx.y * 64, b = blockIdx.z;
    int t = threadIdx.x;
    {
        int cl = t & 63, pb = (t >> 6) * 16;
        float av = a[c0 + cl], cv = c[c0 + cl];
        for (int i = 0; i < 16; ++i) {
            float v = b2f(x2[((size_t)b * N_ + n0 + pb + i) * H_ + c0 + cl]);
            tile[cl][pb + i] = fmaxf(av * v + cv, 0.0f);
        }
    }
    __syncthreads();
    {
        int nl = t & 63, cb = (t >> 6) * 16;
        for (int i = 0; i < 16; ++i)
            out[((size_t)b * H_ + c0 + cb + i) * N_ + n0 + nl] = tile[cb + i][nl];
    }
}

// ---------------------------------------------------------------------------
extern "C" void kernel_launch(void* const* d_in, const int* in_sizes, int n_in,
                              void* d_out, int out_size, void* d_ws, size_t ws_size,
                              hipStream_t stream) {
    const float* unknown = (const float*)d_in[0];
    const float* known   = (const float*)d_in[1];
    const float* uf      = (const float*)d_in[2];
    const float* kf      = (const float*)d_in[3];
    const float* w1      = (const float*)d_in[4];
    const float* g1      = (const float*)d_in[5];
    const float* b1      = (const float*)d_in[6];
    const float* w2      = (const float*)d_in[7];
    const float* g2      = (const float*)d_in[8];
    const float* b2      = (const float*)d_in[9];
    float* out = (float*)d_out;

    char* ws = (char*)d_ws;
    // [0, 36K): shadow stats (4 x 8 x 256 f32) + a1,c1,a2,c2; [36K): counters
    float* fb    = (float*)ws;
    float* sum1P = fb;             // 2048
    float* sq1P  = fb + 2048;      // 2048
    float* sum2P = fb + 4096;      // 2048
    float* sq2P  = fb + 6144;      // 2048
    float* a1    = fb + 8192;      // 256
    float* c1    = fb + 8448;
    float* a2    = fb + 8704;
    float* c2    = fb + 8960;      // 9216 floats total
    uint_t* cnts = (uint_t*)(ws + 36864);   // 2 counters
    // [64K, 576K): converted weights
    ushort_t* w1b = (ushort_t*)(ws + 65536);                        // 384 KB
    ushort_t* w2b = (ushort_t*)(ws + 65536 + (size_t)H_ * K1_ * 2); // 128 KB
    const size_t MB = 1024 * 1024;
    // Lifetimes (stream-serialized):
    //   Acat [1,97): trans_k (cols 0..255) + knn_k gather (256..767) -> gemm1.
    //   kfT  [97,113): trans_k -> knn_k.
    //   x1   [97,129): gemm1 (kfT dead by then).
    //   h1   [1,33):  bnrelu (Acat dead) -> gemm2.
    //   x2   [33,65): gemm2 -> final.
    // Peak 129 MB.
    ushort_t* Acat = (ushort_t*)(ws + 1 * MB);      // 96 MB
    ushort_t* kfT  = (ushort_t*)(ws + 97 * MB);     // 16 MB
    ushort_t* x1   = (ushort_t*)(ws + 97 * MB);     // 32 MB
    ushort_t* h1   = (ushort_t*)(ws + 1 * MB);      // 32 MB
    ushort_t* x2   = (ushort_t*)(ws + 33 * MB);     // 32 MB

    initw_k<<<1025, 256, 0, stream>>>(w1, w2, w1b, w2b, fb, cnts);
    trans_k<<<1536, 256, 0, stream>>>(kf, kfT, uf, Acat);
    knn_k<<<2048, 256, 0, stream>>>(unknown, known, kfT, Acat);
    gemm_k<<<512, 512, 0, stream>>>(Acat, w1b, x1, K1_, sum1P, sq1P,
                                    g1, b1, a1, c1, &cnts[0]);
    bnrelu_k<<<8192, 256, 0, stream>>>((const uint4*)x1, a1, c1, (uint4*)h1);
    gemm_k<<<512, 512, 0, stream>>>(h1, w2b, x2, H_, sum2P, sq2P,
                                    g2, b2, a2, c2, &cnts[1]);
    final_k<<<dim3(64, 4, 16), 256, 0, stream>>>(x2, a2, c2, out);
}

// Round 15
// 288.160 us; speedup vs baseline: 1.1625x; 1.1625x over previous
//
#include <hip/hip_runtime.h>
#include <stdint.h>

#define B_   16
#define N_   4096
#define M_   1024
#define C1_  256
#define C2_  512
#define H_   256
#define K1_  768      // C1+C2
#define P_   65536    // B*N

typedef unsigned int  uint_t;
typedef unsigned short ushort_t;
typedef __attribute__((ext_vector_type(4))) float f32x4;
typedef __attribute__((ext_vector_type(8))) short s16x8;

__device__ __forceinline__ float b2f(ushort_t u) {
    union { uint_t i; float f; } v; v.i = ((uint_t)u) << 16; return v.f;
}
__device__ __forceinline__ ushort_t f2b(float f) {
    union { float f; uint_t i; } v; v.f = f;
    uint_t x = v.i;
    return (ushort_t)((x + 0x7fffu + ((x >> 16) & 1u)) >> 16);  // RNE
}

__device__ __forceinline__ void async16(const void* g, void* l) {
    __builtin_amdgcn_global_load_lds(
        (const __attribute__((address_space(1))) uint_t*)g,
        (__attribute__((address_space(3))) uint_t*)l, 16, 0, 0);
}

// ---------------------------------------------------------------------------
// initw_k: blocks 0..1023 convert w1/w2 to bf16; block 1024 zeroes the
// shadow-stat arrays (9216 f32) and the two gemm completion counters.
// ---------------------------------------------------------------------------
__global__ __launch_bounds__(256) void initw_k(
    const float* __restrict__ w1, const float* __restrict__ w2,
    ushort_t* __restrict__ w1b, ushort_t* __restrict__ w2b,
    float* __restrict__ fb, uint_t* __restrict__ cnts) {
    int blk = blockIdx.x;
    if (blk < 1024) {
        int t = blk * 256 + threadIdx.x;   // 262144 total
        if (t < H_ * K1_) w1b[t] = f2b(w1[t]);
        else { int u = t - H_ * K1_; w2b[u] = f2b(w2[u]); }
    } else {
        for (int i = threadIdx.x; i < 9216; i += 256) fb[i] = 0.0f;
        if (threadIdx.x < 2) cnts[threadIdx.x] = 0u;
    }
}

// ---------------------------------------------------------------------------
// trans_k: merged LDS-tile transposes (round-13 version — measured 46.7 us;
// the round-14 LDS-free variant scattered its stores, 64 x 16B transactions
// per wave store, and halved throughput — reverted).
//  blocks [0,2048):    known_feats (B,512,1024) f32 -> kfT (B,1024,512) bf16
//  blocks [2048,6144): uf (B,256,4096) f32 -> Acat (P,768) bf16 cols 0..255
// ---------------------------------------------------------------------------
__global__ __launch_bounds__(256) void trans_k(
    const float* __restrict__ kf, ushort_t* __restrict__ kfT,
    const float* __restrict__ uf, ushort_t* __restrict__ Acat) {
    __shared__ ushort_t tile[64][65];
    int bid = blockIdx.x;
    int t = threadIdx.x;
    if (bid < 2048) {
        int m0 = (bid & 15) * 64, c0 = ((bid >> 4) & 7) * 64, b = bid >> 7;
        {
            int ml = t & 63, cb = (t >> 6) * 16;
            const float* ip = kf + ((size_t)b * C2_ + c0) * M_ + m0;
            for (int i = 0; i < 16; ++i)
                tile[cb + i][ml] = f2b(ip[(size_t)(cb + i) * M_ + ml]);
        }
        __syncthreads();
        {
            int cl = t & 63, mb = (t >> 6) * 16;
            for (int i = 0; i < 16; ++i)
                kfT[((size_t)b * M_ + m0 + mb + i) * C2_ + c0 + cl] = tile[cl][mb + i];
        }
    } else {
        int id = bid - 2048;
        int n0 = (id & 63) * 64, c0 = ((id >> 6) & 3) * 64, b = id >> 8;
        {
            int nl = t & 63, cb = (t >> 6) * 16;
            const float* ip = uf + ((size_t)b * C1_ + c0) * N_ + n0;
            for (int i = 0; i < 16; ++i)
                tile[cb + i][nl] = f2b(ip[(size_t)(cb + i) * N_ + nl]);
        }
        __syncthreads();
        {
            int cl = t & 63, pb = (t >> 6) * 16;
            for (int i = 0; i < 16; ++i)
                Acat[((size_t)b * N_ + n0 + pb + i) * K1_ + c0 + cl] = tile[cl][pb + i];
        }
    }
}

// ---------------------------------------------------------------------------
// FUSED 3-NN + weighted gather (round-12 structure: med3-insk, barrier-free
// reg handoff, bijective XCD swizzle). Weights in f32 (kept from round 14:
// removes ~300 fp64-divide instrs per group; ~1e-7 perturbation).
// ---------------------------------------------------------------------------
__device__ __forceinline__ uint_t umin_(uint_t a, uint_t b) { return a < b ? a : b; }
__device__ __forceinline__ uint_t umax_(uint_t a, uint_t b) { return a > b ? a : b; }

__device__ __forceinline__ uint_t med3u(uint_t a, uint_t b, uint_t c) {
    uint_t d;
    asm("v_med3_u32 %0, %1, %2, %3" : "=v"(d) : "v"(a), "v"(b), "v"(c));
    return d;
}

// sorted insert keeping 4 smallest: new k_i = med3(key, k_{i-1}, k_i)
__device__ __forceinline__ void insk(uint_t key,
        uint_t& k0, uint_t& k1, uint_t& k2, uint_t& k3) {
    uint_t n3 = med3u(key, k2, k3);
    uint_t n2 = med3u(key, k1, k2);
    uint_t n1 = med3u(key, k0, k1);
    k0 = umin_(k0, key);
    k1 = n1; k2 = n2; k3 = n3;
}

// merge partner's sorted quad (via shfl_xor) with mine: bitonic lowest-4.
__device__ __forceinline__ void mrg4(int off,
        uint_t& a0, uint_t& a1, uint_t& a2, uint_t& a3) {
    uint_t e0 = (uint_t)__shfl_xor((int)a0, off);
    uint_t e1 = (uint_t)__shfl_xor((int)a1, off);
    uint_t e2 = (uint_t)__shfl_xor((int)a2, off);
    uint_t e3 = (uint_t)__shfl_xor((int)a3, off);
    uint_t c0 = umin_(a0, e3), c1 = umin_(a1, e2);
    uint_t c2 = umin_(a2, e1), c3 = umin_(a3, e0);   // bitonic, holds 4 smallest
    uint_t l0 = umin_(c0, c2), h0 = umax_(c0, c2);
    uint_t l1 = umin_(c1, c3), h1 = umax_(c1, c3);
    a0 = umin_(l0, l1); a1 = umax_(l0, l1);
    a2 = umin_(h0, h1); a3 = umax_(h0, h1);
}

__device__ __forceinline__ void ins3d(double d, int m,
                                      double& d0, int& i0, double& d1, int& i1,
                                      double& d2, int& i2) {
    if (d < d2 || (d == d2 && m < i2)) {
        d2 = d; i2 = m;
        if (d2 < d1 || (d2 == d1 && i2 < i1)) { double td = d1; d1 = d2; d2 = td; int ti = i1; i1 = i2; i2 = ti; }
        if (d1 < d0 || (d1 == d0 && i1 < i0)) { double td = d0; d0 = d1; d1 = td; int ti = i0; i0 = i1; i1 = ti; }
    }
}

__global__ __launch_bounds__(256) void knn_k(
    const float* __restrict__ unknown, const float* __restrict__ known,
    const ushort_t* __restrict__ kfT, ushort_t* __restrict__ Acat) {
    __shared__ float4 kpt[M_];             // (x, y, z, |k|^2 fp32) — 16 KB
    // bijective XCD swizzle (2048 % 8 == 0): XCD x serves batches {2x, 2x+1}
    int blk = ((blockIdx.x & 7) << 8) | (blockIdx.x >> 3);
    int b = blk >> 7;                      // batch
    int n0 = (blk & 127) * 32;             // 32 queries per block
    int t = threadIdx.x;
    int qg = t >> 4;                       // query pair 0..15
    int sub = t & 15;                      // candidate slice 0..15

    for (int m = t; m < M_; m += 256) {
        float x = known[((size_t)b * M_ + m) * 3 + 0];
        float y = known[((size_t)b * M_ + m) * 3 + 1];
        float z = known[((size_t)b * M_ + m) * 3 + 2];
        kpt[m] = make_float4(x, y, z, x * x + y * y + z * z);
    }
    __syncthreads();

    int n = n0 + qg * 2;
    float qx0 = unknown[((size_t)b * N_ + n) * 3 + 0];
    float qy0 = unknown[((size_t)b * N_ + n) * 3 + 1];
    float qz0 = unknown[((size_t)b * N_ + n) * 3 + 2];
    float qx1 = unknown[((size_t)b * N_ + n + 1) * 3 + 0];
    float qy1 = unknown[((size_t)b * N_ + n + 1) * 3 + 1];
    float qz1 = unknown[((size_t)b * N_ + n + 1) * 3 + 2];
    float qs0 = qx0 * qx0 + qy0 * qy0 + qz0 * qz0;
    float qs1 = qx1 * qx1 + qy1 * qy1 + qz1 * qz1;

    const uint_t DMASK = 0xFFFFFC00u;
    uint_t A0 = 0xFFFFFFFFu, A1 = 0xFFFFFFFFu, A2 = 0xFFFFFFFFu, A3 = 0xFFFFFFFFu;
    uint_t B0 = 0xFFFFFFFFu, B1 = 0xFFFFFFFFu, B2 = 0xFFFFFFFFu, B3 = 0xFFFFFFFFu;

#pragma unroll 4
    for (int j = 0; j < 64; ++j) {
        int m = j * 16 + sub;
        float4 kp = kpt[m];
        float dot0 = fmaf(qx0, kp.x, fmaf(qy0, kp.y, qz0 * kp.z));
        float d0 = fmaxf(fmaf(-2.0f, dot0, qs0 + kp.w), 0.0f);
        uint_t k0 = (__float_as_uint(d0) & DMASK) | (uint_t)m;
        insk(k0, A0, A1, A2, A3);
        float dot1 = fmaf(qx1, kp.x, fmaf(qy1, kp.y, qz1 * kp.z));
        float d1 = fmaxf(fmaf(-2.0f, dot1, qs1 + kp.w), 0.0f);
        uint_t k1 = (__float_as_uint(d1) & DMASK) | (uint_t)m;
        insk(k1, B0, B1, B2, B3);
    }

    // merge across the 16 subs (lane bits 0..3)
#pragma unroll
    for (int off = 1; off < 16; off <<= 1) {
        mrg4(off, A0, A1, A2, A3);
        mrg4(off, B0, B1, B2, B3);
    }
    // all 16 subs of a query pair now hold the same top-4 keys

    int   F0r[2], F1r[2], F2r[2];
    float wxr[2], wyr[2], wzr[2];
#pragma unroll
    for (int qi = 0; qi < 2; ++qi) {
        uint_t K0 = qi ? B0 : A0, K1 = qi ? B1 : A1;
        uint_t K2 = qi ? B2 : A2, K3 = qi ? B3 : A3;
        float qx = qi ? qx1 : qx0, qy = qi ? qy1 : qy0;
        float qz = qi ? qz1 : qz0, qs = qi ? qs1 : qs0;

        float d0t = __uint_as_float(K0 & DMASK);
        float d1t = __uint_as_float(K1 & DMASK);
        float d2t = __uint_as_float(K2 & DMASK);
        float d3t = __uint_as_float(K3 & DMASK);
        float margin = fmaf(d3t, 2.5e-4f, 4.0e-5f);
        bool flagged = (d3t - d2t) <= margin;

        float e0, e1, e2; int F0, F1, F2;
        if (!flagged) {
            e0 = d0t; e1 = d1t; e2 = d2t;
            F0 = (int)(K0 & 0x3FFu);
            F1 = (int)(K1 & 0x3FFu);
            F2 = (int)(K2 & 0x3FFu);
        } else {
            // exact fallback: fp32 rescan + fp64 lexicographic insert for
            // candidates that can possibly be in the true top-3.
            float fthr = d2t + margin;
            double qdx = (double)qx, qdy = (double)qy, qdz = (double)qz;
            double qds = qdx * qdx + qdy * qdy + qdz * qdz;
            double Z0 = 1e300, Z1 = 1e300, Z2 = 1e300;
            int    G0 = 0x7fffffff, G1 = 0x7fffffff, G2 = 0x7fffffff;
            for (int m = sub; m < M_; m += 16) {
                float4 kp = kpt[m];
                float dot = fmaf(qx, kp.x, fmaf(qy, kp.y, qz * kp.z));
                float df = fmaf(-2.0f, dot, qs + kp.w);
                if (df <= fthr) {
                    double X = (double)kp.x, Y = (double)kp.y, Z = (double)kp.z;
                    double ks = X * X + Y * Y + Z * Z;      // same order as fp64 ref
                    double dd = qdx * X + qdy * Y + qdz * Z;
                    double de = qds + ks - 2.0 * dd;
                    ins3d(de, m, Z0, G0, Z1, G1, Z2, G2);
                }
            }
#pragma unroll
            for (int off = 1; off < 16; off <<= 1) {
                double f0 = __shfl_xor(Z0, off), f1 = __shfl_xor(Z1, off), f2 = __shfl_xor(Z2, off);
                int    j0 = __shfl_xor(G0, off), j1 = __shfl_xor(G1, off), j2 = __shfl_xor(G2, off);
                ins3d(f0, j0, Z0, G0, Z1, G1, Z2, G2);
                ins3d(f1, j1, Z0, G0, Z1, G1, Z2, G2);
                ins3d(f2, j2, Z0, G0, Z1, G1, Z2, G2);
            }
            e0 = (float)Z0; e1 = (float)Z1; e2 = (float)Z2;
            F0 = G0; F1 = G1; F2 = G2;
        }

        float w0 = 1.0f / (e0 + 1e-8f);
        float w1 = 1.0f / (e1 + 1e-8f);
        float w2 = 1.0f / (e2 + 1e-8f);
        float inv = 1.0f / (w0 + w1 + w2);
        F0r[qi] = F0; F1r[qi] = F1; F2r[qi] = F2;
        wxr[qi] = w0 * inv;
        wyr[qi] = w1 * inv;
        wzr[qi] = w2 * inv;
    }

    // ---- gather phase (no barrier): wave wid owns queries wid*8..wid*8+7;
    // idx/weights broadcast from lane p*16 via shfl (uniform in each group).
    {
        int lane = t & 63, wid = t >> 6;
        size_t pbase = (size_t)b * N_ + n0 + wid * 8;
        const ushort_t* kfb = kfT + (size_t)b * M_ * C2_;
#pragma unroll
        for (int p = 0; p < 4; ++p) {
#pragma unroll
            for (int qi = 0; qi < 2; ++qi) {
                int src = p << 4;
                int i0 = __shfl(F0r[qi], src);
                int i1 = __shfl(F1r[qi], src);
                int i2 = __shfl(F2r[qi], src);
                float wx = __shfl(wxr[qi], src);
                float wy = __shfl(wyr[qi], src);
                float wz = __shfl(wzr[qi], src);
                const uint4* r0 = (const uint4*)(kfb + (size_t)i0 * C2_);
                const uint4* r1 = (const uint4*)(kfb + (size_t)i1 * C2_);
                const uint4* r2 = (const uint4*)(kfb + (size_t)i2 * C2_);
                uint4 v0 = r0[lane], v1 = r1[lane], v2 = r2[lane];
                const ushort_t* p0 = (const ushort_t*)&v0;
                const ushort_t* p1 = (const ushort_t*)&v1;
                const ushort_t* p2 = (const ushort_t*)&v2;
                uint4 o; ushort_t* po = (ushort_t*)&o;
                for (int j = 0; j < 8; ++j) {
                    float f = wx * b2f(p0[j]) + wy * b2f(p1[j]) + wz * b2f(p2[j]);
                    po[j] = f2b(f);
                }
                ((uint4*)(Acat + (pbase + p * 2 + qi) * K1_ + C1_))[lane] = o;
            }
        }
    }
}

// ---------------------------------------------------------------------------
// Unified GEMM + fused column stats + LAST-BLOCK BN-coef computation.
// Pipeline: 3-buffer, depth 2, counted vmcnt + raw s_barrier. Stats: quad
// shfl-reduce -> LDS [2][256] -> block combine -> atomicAdd into 8 shadow
// copies -> last block folds shadows (coherent atomic-read path) and
// computes a/c with the exact coef arithmetic.
// ---------------------------------------------------------------------------
__global__ __launch_bounds__(512, 4) void gemm_k(
    const ushort_t* __restrict__ A, const ushort_t* __restrict__ Bw,
    ushort_t* __restrict__ C, int K,
    float* __restrict__ sumP, float* __restrict__ sqP,
    const float* __restrict__ g, const float* __restrict__ bt,
    float* __restrict__ a, float* __restrict__ c,
    uint_t* __restrict__ cnt) {
    __shared__ ushort_t As[3][128 * 32];
    __shared__ ushort_t Bs[3][256 * 32];
    __shared__ uint_t lastFlag;
    int t = threadIdx.x, lane = t & 63, wid = t >> 6;
    int wm = wid & 1, wn = wid >> 1;           // 2 x 4 wave grid -> 64x64 each
    int row0 = blockIdx.x * 128;
    int quad = lane >> 4, l15 = lane & 15;
    int srow = lane >> 2, kc = lane & 3;
    int kcs = kc ^ ((srow >> 1) & 3);          // swizzled source chunk
    int rsw = (l15 >> 1) & 3;                  // read-side swizzle key

    f32x4 acc[4][4] = {};

    auto stage = [&](int buf, int k0) {
        async16(A + ((size_t)(row0 + wid * 16 + srow)) * K + k0 + kcs * 8,
                &As[buf][wid * 16 * 32]);
#pragma unroll
        for (int j = 0; j < 2; ++j) {
            int rbase = wid * 32 + j * 16;
            async16(Bw + ((size_t)(rbase + srow)) * K + k0 + kcs * 8,
                    &Bs[buf][rbase * 32]);
        }
    };

    int nt = K >> 5;                 // 24 or 8
    stage(0, 0);
    stage(1, 32);

    int bi = 0;
    for (int it = 0; it < nt; ++it) {
        int pf = it + 2;
        if (pf < nt) stage(pf % 3, pf * 32);

        if (it < nt - 2)      asm volatile("s_waitcnt vmcnt(6)" ::: "memory");
        else if (it == nt - 2) asm volatile("s_waitcnt vmcnt(3)" ::: "memory");
        else                  asm volatile("s_waitcnt vmcnt(0)" ::: "memory");
        __builtin_amdgcn_s_barrier();          // all waves' tile-it loads landed
        asm volatile("" ::: "memory");

        s16x8 af[4], bfr[4];
#pragma unroll
        for (int i = 0; i < 4; ++i)
            af[i] = *(const s16x8*)&As[bi][(wm * 64 + i * 16 + l15) * 32 + ((quad ^ rsw) * 8)];
#pragma unroll
        for (int j = 0; j < 4; ++j)
            bfr[j] = *(const s16x8*)&Bs[bi][(wn * 64 + j * 16 + l15) * 32 + ((quad ^ rsw) * 8)];
#pragma unroll
        for (int i = 0; i < 4; ++i)
#pragma unroll
            for (int j = 0; j < 4; ++j)
                acc[i][j] = __builtin_amdgcn_mfma_f32_16x16x32_bf16(
                    af[i], bfr[j], acc[i][j], 0, 0, 0);

        asm volatile("" ::: "memory");
        __builtin_amdgcn_s_barrier();          // reads of buf bi done -> reusable
        asm volatile("" ::: "memory");
        bi = (bi + 1 == 3) ? 0 : bi + 1;
    }

    float colS[4] = {0.f, 0.f, 0.f, 0.f};
    float colQ[4] = {0.f, 0.f, 0.f, 0.f};
#pragma unroll
    for (int i = 0; i < 4; ++i)
#pragma unroll
        for (int j = 0; j < 4; ++j)
#pragma unroll
            for (int r = 0; r < 4; ++r) {
                int m = row0 + wm * 64 + i * 16 + quad * 4 + r;
                int nn = wn * 64 + j * 16 + l15;
                ushort_t cv = f2b(acc[i][j][r]);
                C[(size_t)m * H_ + nn] = cv;
                float v = b2f(cv);
                colS[j] += v;
                colQ[j] += v * v;
            }
    // reduce over quad (lane bits 4,5)
#pragma unroll
    for (int j = 0; j < 4; ++j) {
        colS[j] += __shfl_xor(colS[j], 16);
        colS[j] += __shfl_xor(colS[j], 32);
        colQ[j] += __shfl_xor(colQ[j], 16);
        colQ[j] += __shfl_xor(colQ[j], 32);
    }
    // block-level reduce via LDS (As is dead after the final barrier)
    float* ps = (float*)&As[0][0];   // [2][256]
    float* pq = ps + 512;            // [2][256]
    if (quad == 0) {
#pragma unroll
        for (int j = 0; j < 4; ++j) {
            int nn = wn * 64 + j * 16 + l15;
            ps[wm * 256 + nn] = colS[j];
            pq[wm * 256 + nn] = colQ[j];
        }
    }
    __syncthreads();
    if (t < 256) {
        float s = ps[t] + ps[256 + t];
        float q = pq[t] + pq[256 + t];
        int sh = (blockIdx.x & 7) * 256 + t;   // 8 shadow copies
        atomicAdd(&sumP[sh], s);
        atomicAdd(&sqP[sh], q);
    }
    // last-block BN-coef: syncthreads drains this block's atomics (vmcnt(0)
    // before s_barrier), so counter==gridDim implies all shadow adds landed.
    __syncthreads();
    if (t == 0)
        lastFlag = (atomicAdd(cnt, 1u) == (uint_t)(gridDim.x - 1)) ? 1u : 0u;
    __syncthreads();
    if (lastFlag != 0u && t < 256) {
        float s = 0.f, q = 0.f;
#pragma unroll
        for (int k = 0; k < 8; ++k) {
            s += atomicAdd(&sumP[k * 256 + t], 0.0f);   // coherent read path
            q += atomicAdd(&sqP[k * 256 + t], 0.0f);
        }
        float mean = s * (1.0f / P_);
        float var  = q * (1.0f / P_) - mean * mean;
        float ai = g[t] * rsqrtf(var + 1e-5f);
        a[t] = ai;
        c[t] = bt[t] - mean * ai;
    }
}

// BN + ReLU elementwise: x1 (P,256) bf16 -> h1 bf16, one uint4 (8 elems)/thread
__global__ __launch_bounds__(256) void bnrelu_k(
    const uint4* __restrict__ x, const float* __restrict__ a,
    const float* __restrict__ c, uint4* __restrict__ h) {
    size_t i = (size_t)blockIdx.x * 256 + threadIdx.x;   // 2,097,152 uint4s
    uint4 v = x[i];
    int chb = (int)((i * 8) & 255);
    const ushort_t* pv = (const ushort_t*)&v;
    uint4 o; ushort_t* po = (ushort_t*)&o;
    for (int j = 0; j < 8; ++j) {
        float f = b2f(pv[j]);
        f = a[chb + j] * f + c[chb + j];
        po[j] = f2b(fmaxf(f, 0.0f));
    }
    h[i] = o;
}

// BN + ReLU + transpose: x2 (P,256) bf16 -> out (B,256,N) f32, 64x64 tiles
__global__ __launch_bounds__(256) void final_k(
    const ushort_t* __restrict__ x2, const float* __restrict__ a,
    const float* __restrict__ c, float* __restrict__ out) {
    __shared__ float tile[64][65];
    int n0 = blockIdx.x * 64, c0 = blockIdx.y * 64, b = blockIdx.z;
    int t = threadIdx.x;
    {
        int cl = t & 63, pb = (t >> 6) * 16;
        float av = a[c0 + cl], cv = c[c0 + cl];
        for (int i = 0; i < 16; ++i) {
            float v = b2f(x2[((size_t)b * N_ + n0 + pb + i) * H_ + c0 + cl]);
            tile[cl][pb + i] = fmaxf(av * v + cv, 0.0f);
        }
    }
    __syncthreads();
    {
        int nl = t & 63, cb = (t >> 6) * 16;
        for (int i = 0; i < 16; ++i)
            out[((size_t)b * H_ + c0 + cb + i) * N_ + n0 + nl] = tile[cb + i][nl];
    }
}

// ---------------------------------------------------------------------------
extern "C" void kernel_launch(void* const* d_in, const int* in_sizes, int n_in,
                              void* d_out, int out_size, void* d_ws, size_t ws_size,
                              hipStream_t stream) {
    const float* unknown = (const float*)d_in[0];
    const float* known   = (const float*)d_in[1];
    const float* uf      = (const float*)d_in[2];
    const float* kf      = (const float*)d_in[3];
    const float* w1      = (const float*)d_in[4];
    const float* g1      = (const float*)d_in[5];
    const float* b1      = (const float*)d_in[6];
    const float* w2      = (const float*)d_in[7];
    const float* g2      = (const float*)d_in[8];
    const float* b2      = (const float*)d_in[9];
    float* out = (float*)d_out;

    char* ws = (char*)d_ws;
    // [0, 36K): shadow stats (4 x 8 x 256 f32) + a1,c1,a2,c2; [36K): counters
    float* fb    = (float*)ws;
    float* sum1P = fb;             // 2048
    float* sq1P  = fb + 2048;      // 2048
    float* sum2P = fb + 4096;      // 2048
    float* sq2P  = fb + 6144;      // 2048
    float* a1    = fb + 8192;      // 256
    float* c1    = fb + 8448;
    float* a2    = fb + 8704;
    float* c2    = fb + 8960;      // 9216 floats total
    uint_t* cnts = (uint_t*)(ws + 36864);   // 2 counters
    // [64K, 576K): converted weights
    ushort_t* w1b = (ushort_t*)(ws + 65536);                        // 384 KB
    ushort_t* w2b = (ushort_t*)(ws + 65536 + (size_t)H_ * K1_ * 2); // 128 KB
    const size_t MB = 1024 * 1024;
    // Lifetimes (stream-serialized):
    //   Acat [1,97): trans_k (cols 0..255) + knn_k gather (256..767) -> gemm1.
    //   kfT  [97,113): trans_k -> knn_k.
    //   x1   [97,129): gemm1 (kfT dead by then).
    //   h1   [1,33):  bnrelu (Acat dead) -> gemm2.
    //   x2   [33,65): gemm2 -> final.
    // Peak 129 MB.
    ushort_t* Acat = (ushort_t*)(ws + 1 * MB);      // 96 MB
    ushort_t* kfT  = (ushort_t*)(ws + 97 * MB);     // 16 MB
    ushort_t* x1   = (ushort_t*)(ws + 97 * MB);     // 32 MB
    ushort_t* h1   = (ushort_t*)(ws + 1 * MB);      // 32 MB
    ushort_t* x2   = (ushort_t*)(ws + 33 * MB);     // 32 MB

    initw_k<<<1025, 256, 0, stream>>>(w1, w2, w1b, w2b, fb, cnts);
    trans_k<<<6144, 256, 0, stream>>>(kf, kfT, uf, Acat);
    knn_k<<<2048, 256, 0, stream>>>(unknown, known, kfT, Acat);
    gemm_k<<<512, 512, 0, stream>>>(Acat, w1b, x1, K1_, sum1P, sq1P,
                                    g1, b1, a1, c1, &cnts[0]);
    bnrelu_k<<<8192, 256, 0, stream>>>((const uint4*)x1, a1, c1, (uint4*)h1);
    gemm_k<<<512, 512, 0, stream>>>(h1, w2b, x2, H_, sum2P, sq2P,
                                    g2, b2, a2, c2, &cnts[1]);
    final_k<<<dim3(64, 4, 16), 256, 0, stream>>>(x2, a2, c2, out);
}

// Round 16
// 275.746 us; speedup vs baseline: 1.2149x; 1.0450x over previous
//
#include <hip/hip_runtime.h>
#include <stdint.h>

#define B_   16
#define N_   4096
#define M_   1024
#define C1_  256
#define C2_  512
#define H_   256
#define K1_  768      // C1+C2
#define P_   65536    // B*N

typedef unsigned int  uint_t;
typedef unsigned short ushort_t;
typedef __attribute__((ext_vector_type(4))) float f32x4;
typedef __attribute__((ext_vector_type(8))) short s16x8;

__device__ __forceinline__ float b2f(ushort_t u) {
    union { uint_t i; float f; } v; v.i = ((uint_t)u) << 16; return v.f;
}
__device__ __forceinline__ ushort_t f2b(float f) {
    union { float f; uint_t i; } v; v.f = f;
    uint_t x = v.i;
    return (ushort_t)((x + 0x7fffu + ((x >> 16) & 1u)) >> 16);  // RNE
}

__device__ __forceinline__ void async16(const void* g, void* l) {
    __builtin_amdgcn_global_load_lds(
        (const __attribute__((address_space(1))) uint_t*)g,
        (__attribute__((address_space(3))) uint_t*)l, 16, 0, 0);
}

// ---------------------------------------------------------------------------
// initw_k: blocks 0..1023 convert w1/w2 to bf16; block 1024 zeroes the
// shadow-stat arrays (9216 f32) and the two gemm completion counters.
// ---------------------------------------------------------------------------
__global__ __launch_bounds__(256) void initw_k(
    const float* __restrict__ w1, const float* __restrict__ w2,
    ushort_t* __restrict__ w1b, ushort_t* __restrict__ w2b,
    float* __restrict__ fb, uint_t* __restrict__ cnts) {
    int blk = blockIdx.x;
    if (blk < 1024) {
        int t = blk * 256 + threadIdx.x;   // 262144 total
        if (t < H_ * K1_) w1b[t] = f2b(w1[t]);
        else { int u = t - H_ * K1_; w2b[u] = f2b(w2[u]); }
    } else {
        for (int i = threadIdx.x; i < 9216; i += 256) fb[i] = 0.0f;
        if (threadIdx.x < 2) cnts[threadIdx.x] = 0u;
    }
}

// ---------------------------------------------------------------------------
// trans_k: kf-only LDS-tile transpose (uf half moved into knn_k).
//  known_feats (B,512,1024) f32 -> kfT (B,1024,512) bf16, 2048 blocks.
// ---------------------------------------------------------------------------
__global__ __launch_bounds__(256) void trans_k(
    const float* __restrict__ kf, ushort_t* __restrict__ kfT) {
    __shared__ ushort_t tile[64][65];
    int bid = blockIdx.x;
    int t = threadIdx.x;
    int m0 = (bid & 15) * 64, c0 = ((bid >> 4) & 7) * 64, b = bid >> 7;
    {
        int ml = t & 63, cb = (t >> 6) * 16;
        const float* ip = kf + ((size_t)b * C2_ + c0) * M_ + m0;
        for (int i = 0; i < 16; ++i)
            tile[cb + i][ml] = f2b(ip[(size_t)(cb + i) * M_ + ml]);
    }
    __syncthreads();
    {
        int cl = t & 63, mb = (t >> 6) * 16;
        for (int i = 0; i < 16; ++i)
            kfT[((size_t)b * M_ + m0 + mb + i) * C2_ + c0 + cl] = tile[cl][mb + i];
    }
}

// ---------------------------------------------------------------------------
// FUSED 3-NN + weighted gather + uf-transpose.
// knn core: med3-insk, barrier-free select->gather flow, bijective XCD
// swizzle, f32 weights. NEW: each block also fills Acat cols 0..255 for its
// own 32 points — the 32 uf loads/thread are ISSUED before the gather loop
// (HBM latency drains under gather's traffic), then after one barrier
// (kpt dead) they are packed bf16 into a reused LDS tile (pitch 272 -> all
// ds ops 16B-aligned) and written out as 1KB-contiguous wave stores.
// Same f2b RNE -> Acat bit-identical to the old trans_k output.
// ---------------------------------------------------------------------------
__device__ __forceinline__ uint_t umin_(uint_t a, uint_t b) { return a < b ? a : b; }
__device__ __forceinline__ uint_t umax_(uint_t a, uint_t b) { return a > b ? a : b; }

__device__ __forceinline__ uint_t med3u(uint_t a, uint_t b, uint_t c) {
    uint_t d;
    asm("v_med3_u32 %0, %1, %2, %3" : "=v"(d) : "v"(a), "v"(b), "v"(c));
    return d;
}

// sorted insert keeping 4 smallest: new k_i = med3(key, k_{i-1}, k_i)
__device__ __forceinline__ void insk(uint_t key,
        uint_t& k0, uint_t& k1, uint_t& k2, uint_t& k3) {
    uint_t n3 = med3u(key, k2, k3);
    uint_t n2 = med3u(key, k1, k2);
    uint_t n1 = med3u(key, k0, k1);
    k0 = umin_(k0, key);
    k1 = n1; k2 = n2; k3 = n3;
}

// merge partner's sorted quad (via shfl_xor) with mine: bitonic lowest-4.
__device__ __forceinline__ void mrg4(int off,
        uint_t& a0, uint_t& a1, uint_t& a2, uint_t& a3) {
    uint_t e0 = (uint_t)__shfl_xor((int)a0, off);
    uint_t e1 = (uint_t)__shfl_xor((int)a1, off);
    uint_t e2 = (uint_t)__shfl_xor((int)a2, off);
    uint_t e3 = (uint_t)__shfl_xor((int)a3, off);
    uint_t c0 = umin_(a0, e3), c1 = umin_(a1, e2);
    uint_t c2 = umin_(a2, e1), c3 = umin_(a3, e0);   // bitonic, holds 4 smallest
    uint_t l0 = umin_(c0, c2), h0 = umax_(c0, c2);
    uint_t l1 = umin_(c1, c3), h1 = umax_(c1, c3);
    a0 = umin_(l0, l1); a1 = umax_(l0, l1);
    a2 = umin_(h0, h1); a3 = umax_(h0, h1);
}

__device__ __forceinline__ void ins3d(double d, int m,
                                      double& d0, int& i0, double& d1, int& i1,
                                      double& d2, int& i2) {
    if (d < d2 || (d == d2 && m < i2)) {
        d2 = d; i2 = m;
        if (d2 < d1 || (d2 == d1 && i2 < i1)) { double td = d1; d1 = d2; d2 = td; int ti = i1; i1 = i2; i2 = ti; }
        if (d1 < d0 || (d1 == d0 && i1 < i0)) { double td = d0; d0 = d1; d1 = td; int ti = i0; i0 = i1; i1 = ti; }
    }
}

#define TUP_ 272   // tileU pitch in ushorts (544B: 16B-aligned rows)

__global__ __launch_bounds__(256) void knn_k(
    const float* __restrict__ unknown, const float* __restrict__ known,
    const ushort_t* __restrict__ kfT, const float* __restrict__ uf,
    ushort_t* __restrict__ Acat) {
    __shared__ __align__(16) char smem[32 * TUP_ * 2];   // 17,408 B
    float4* kpt = (float4*)smem;           // [1024] (x,y,z,|k|^2) — 16 KB
    // bijective XCD swizzle (2048 % 8 == 0): XCD x serves batches {2x, 2x+1}
    int blk = ((blockIdx.x & 7) << 8) | (blockIdx.x >> 3);
    int b = blk >> 7;                      // batch
    int n0 = (blk & 127) * 32;             // 32 queries per block
    int t = threadIdx.x;
    int qg = t >> 4;                       // query pair 0..15
    int sub = t & 15;                      // candidate slice 0..15

    for (int m = t; m < M_; m += 256) {
        float x = known[((size_t)b * M_ + m) * 3 + 0];
        float y = known[((size_t)b * M_ + m) * 3 + 1];
        float z = known[((size_t)b * M_ + m) * 3 + 2];
        kpt[m] = make_float4(x, y, z, x * x + y * y + z * z);
    }
    __syncthreads();

    int n = n0 + qg * 2;
    float qx0 = unknown[((size_t)b * N_ + n) * 3 + 0];
    float qy0 = unknown[((size_t)b * N_ + n) * 3 + 1];
    float qz0 = unknown[((size_t)b * N_ + n) * 3 + 2];
    float qx1 = unknown[((size_t)b * N_ + n + 1) * 3 + 0];
    float qy1 = unknown[((size_t)b * N_ + n + 1) * 3 + 1];
    float qz1 = unknown[((size_t)b * N_ + n + 1) * 3 + 2];
    float qs0 = qx0 * qx0 + qy0 * qy0 + qz0 * qz0;
    float qs1 = qx1 * qx1 + qy1 * qy1 + qz1 * qz1;

    const uint_t DMASK = 0xFFFFFC00u;
    uint_t A0 = 0xFFFFFFFFu, A1 = 0xFFFFFFFFu, A2 = 0xFFFFFFFFu, A3 = 0xFFFFFFFFu;
    uint_t B0 = 0xFFFFFFFFu, B1 = 0xFFFFFFFFu, B2 = 0xFFFFFFFFu, B3 = 0xFFFFFFFFu;

#pragma unroll 4
    for (int j = 0; j < 64; ++j) {
        int m = j * 16 + sub;
        float4 kp = kpt[m];
        float dot0 = fmaf(qx0, kp.x, fmaf(qy0, kp.y, qz0 * kp.z));
        float d0 = fmaxf(fmaf(-2.0f, dot0, qs0 + kp.w), 0.0f);
        uint_t k0 = (__float_as_uint(d0) & DMASK) | (uint_t)m;
        insk(k0, A0, A1, A2, A3);
        float dot1 = fmaf(qx1, kp.x, fmaf(qy1, kp.y, qz1 * kp.z));
        float d1 = fmaxf(fmaf(-2.0f, dot1, qs1 + kp.w), 0.0f);
        uint_t k1 = (__float_as_uint(d1) & DMASK) | (uint_t)m;
        insk(k1, B0, B1, B2, B3);
    }

    // merge across the 16 subs (lane bits 0..3)
#pragma unroll
    for (int off = 1; off < 16; off <<= 1) {
        mrg4(off, A0, A1, A2, A3);
        mrg4(off, B0, B1, B2, B3);
    }
    // all 16 subs of a query pair now hold the same top-4 keys

    int   F0r[2], F1r[2], F2r[2];
    float wxr[2], wyr[2], wzr[2];
#pragma unroll
    for (int qi = 0; qi < 2; ++qi) {
        uint_t K0 = qi ? B0 : A0, K1 = qi ? B1 : A1;
        uint_t K2 = qi ? B2 : A2, K3 = qi ? B3 : A3;
        float qx = qi ? qx1 : qx0, qy = qi ? qy1 : qy0;
        float qz = qi ? qz1 : qz0, qs = qi ? qs1 : qs0;

        float d0t = __uint_as_float(K0 & DMASK);
        float d1t = __uint_as_float(K1 & DMASK);
        float d2t = __uint_as_float(K2 & DMASK);
        float d3t = __uint_as_float(K3 & DMASK);
        float margin = fmaf(d3t, 2.5e-4f, 4.0e-5f);
        bool flagged = (d3t - d2t) <= margin;

        float e0, e1, e2; int F0, F1, F2;
        if (!flagged) {
            e0 = d0t; e1 = d1t; e2 = d2t;
            F0 = (int)(K0 & 0x3FFu);
            F1 = (int)(K1 & 0x3FFu);
            F2 = (int)(K2 & 0x3FFu);
        } else {
            // exact fallback: fp32 rescan + fp64 lexicographic insert for
            // candidates that can possibly be in the true top-3.
            float fthr = d2t + margin;
            double qdx = (double)qx, qdy = (double)qy, qdz = (double)qz;
            double qds = qdx * qdx + qdy * qdy + qdz * qdz;
            double Z0 = 1e300, Z1 = 1e300, Z2 = 1e300;
            int    G0 = 0x7fffffff, G1 = 0x7fffffff, G2 = 0x7fffffff;
            for (int m = sub; m < M_; m += 16) {
                float4 kp = kpt[m];
                float dot = fmaf(qx, kp.x, fmaf(qy, kp.y, qz * kp.z));
                float df = fmaf(-2.0f, dot, qs + kp.w);
                if (df <= fthr) {
                    double X = (double)kp.x, Y = (double)kp.y, Z = (double)kp.z;
                    double ks = X * X + Y * Y + Z * Z;      // same order as fp64 ref
                    double dd = qdx * X + qdy * Y + qdz * Z;
                    double de = qds + ks - 2.0 * dd;
                    ins3d(de, m, Z0, G0, Z1, G1, Z2, G2);
                }
            }
#pragma unroll
            for (int off = 1; off < 16; off <<= 1) {
                double f0 = __shfl_xor(Z0, off), f1 = __shfl_xor(Z1, off), f2 = __shfl_xor(Z2, off);
                int    j0 = __shfl_xor(G0, off), j1 = __shfl_xor(G1, off), j2 = __shfl_xor(G2, off);
                ins3d(f0, j0, Z0, G0, Z1, G1, Z2, G2);
                ins3d(f1, j1, Z0, G0, Z1, G1, Z2, G2);
                ins3d(f2, j2, Z0, G0, Z1, G1, Z2, G2);
            }
            e0 = (float)Z0; e1 = (float)Z1; e2 = (float)Z2;
            F0 = G0; F1 = G1; F2 = G2;
        }

        float w0 = 1.0f / (e0 + 1e-8f);
        float w1 = 1.0f / (e1 + 1e-8f);
        float w2 = 1.0f / (e2 + 1e-8f);
        float inv = 1.0f / (w0 + w1 + w2);
        F0r[qi] = F0; F1r[qi] = F1; F2r[qi] = F2;
        wxr[qi] = w0 * inv;
        wyr[qi] = w1 * inv;
        wzr[qi] = w2 * inv;
    }

    // ---- issue uf preloads (32 channels of this thread's point) — their
    // HBM latency drains under the gather loop below.
    float vu[32];
    {
        int p = t & 31, cb = (t >> 5) * 32;
        const float* up = uf + ((size_t)b * C1_ + cb) * N_ + n0 + p;
#pragma unroll
        for (int i = 0; i < 32; ++i)
            vu[i] = up[(size_t)i * N_];
    }

    // ---- gather phase (no barrier): wave wid owns queries wid*8..wid*8+7;
    // idx/weights broadcast from lane p*16 via shfl (uniform in each group).
    {
        int lane = t & 63, wid = t >> 6;
        size_t pbase = (size_t)b * N_ + n0 + wid * 8;
        const ushort_t* kfb = kfT + (size_t)b * M_ * C2_;
#pragma unroll
        for (int p = 0; p < 4; ++p) {
#pragma unroll
            for (int qi = 0; qi < 2; ++qi) {
                int src = p << 4;
                int i0 = __shfl(F0r[qi], src);
                int i1 = __shfl(F1r[qi], src);
                int i2 = __shfl(F2r[qi], src);
                float wx = __shfl(wxr[qi], src);
                float wy = __shfl(wyr[qi], src);
                float wz = __shfl(wzr[qi], src);
                const uint4* r0 = (const uint4*)(kfb + (size_t)i0 * C2_);
                const uint4* r1 = (const uint4*)(kfb + (size_t)i1 * C2_);
                const uint4* r2 = (const uint4*)(kfb + (size_t)i2 * C2_);
                uint4 v0 = r0[lane], v1 = r1[lane], v2 = r2[lane];
                const ushort_t* p0 = (const ushort_t*)&v0;
                const ushort_t* p1 = (const ushort_t*)&v1;
                const ushort_t* p2 = (const ushort_t*)&v2;
                uint4 o; ushort_t* po = (ushort_t*)&o;
                for (int j = 0; j < 8; ++j) {
                    float f = wx * b2f(p0[j]) + wy * b2f(p1[j]) + wz * b2f(p2[j]);
                    po[j] = f2b(f);
                }
                ((uint4*)(Acat + (pbase + p * 2 + qi) * K1_ + C1_))[lane] = o;
            }
        }
    }

    // ---- uf-transpose epilogue: kpt dead in ALL waves after this barrier;
    // reuse the LDS as tileU[32][TUP_].
    asm volatile("" ::: "memory");
    __syncthreads();
    {
        ushort_t* tileU = (ushort_t*)smem;
        int p = t & 31, cb = (t >> 5) * 32;
#pragma unroll
        for (int j = 0; j < 4; ++j) {
            uint4 pk;
            pk.x = (uint_t)f2b(vu[j * 8 + 0]) | ((uint_t)f2b(vu[j * 8 + 1]) << 16);
            pk.y = (uint_t)f2b(vu[j * 8 + 2]) | ((uint_t)f2b(vu[j * 8 + 3]) << 16);
            pk.z = (uint_t)f2b(vu[j * 8 + 4]) | ((uint_t)f2b(vu[j * 8 + 5]) << 16);
            pk.w = (uint_t)f2b(vu[j * 8 + 6]) | ((uint_t)f2b(vu[j * 8 + 7]) << 16);
            *(uint4*)&tileU[p * TUP_ + cb + j * 8] = pk;
        }
    }
    __syncthreads();
    {
        const ushort_t* tileU = (const ushort_t*)smem;
        int p = t >> 3, colq = t & 7;
        size_t rowb = ((size_t)b * N_ + n0 + p) * K1_;
#pragma unroll
        for (int j = 0; j < 4; ++j) {
            int co = (colq + 8 * j) * 8;
            uint4 x = *(const uint4*)&tileU[p * TUP_ + co];
            *(uint4*)(Acat + rowb + co) = x;
        }
    }
}

// ---------------------------------------------------------------------------
// Unified GEMM + fused column stats + LAST-BLOCK BN-coef computation.
// Pipeline: 3-buffer, depth 2, counted vmcnt + raw s_barrier. Stats: quad
// shfl-reduce -> LDS [2][256] -> block combine -> atomicAdd into 8 shadow
// copies -> last block folds shadows (coherent atomic-read path) and
// computes a/c with the exact coef arithmetic.
// ---------------------------------------------------------------------------
__global__ __launch_bounds__(512, 4) void gemm_k(
    const ushort_t* __restrict__ A, const ushort_t* __restrict__ Bw,
    ushort_t* __restrict__ C, int K,
    float* __restrict__ sumP, float* __restrict__ sqP,
    const float* __restrict__ g, const float* __restrict__ bt,
    float* __restrict__ a, float* __restrict__ c,
    uint_t* __restrict__ cnt) {
    __shared__ ushort_t As[3][128 * 32];
    __shared__ ushort_t Bs[3][256 * 32];
    __shared__ uint_t lastFlag;
    int t = threadIdx.x, lane = t & 63, wid = t >> 6;
    int wm = wid & 1, wn = wid >> 1;           // 2 x 4 wave grid -> 64x64 each
    int row0 = blockIdx.x * 128;
    int quad = lane >> 4, l15 = lane & 15;
    int srow = lane >> 2, kc = lane & 3;
    int kcs = kc ^ ((srow >> 1) & 3);          // swizzled source chunk
    int rsw = (l15 >> 1) & 3;                  // read-side swizzle key

    f32x4 acc[4][4] = {};

    auto stage = [&](int buf, int k0) {
        async16(A + ((size_t)(row0 + wid * 16 + srow)) * K + k0 + kcs * 8,
                &As[buf][wid * 16 * 32]);
#pragma unroll
        for (int j = 0; j < 2; ++j) {
            int rbase = wid * 32 + j * 16;
            async16(Bw + ((size_t)(rbase + srow)) * K + k0 + kcs * 8,
                    &Bs[buf][rbase * 32]);
        }
    };

    int nt = K >> 5;                 // 24 or 8
    stage(0, 0);
    stage(1, 32);

    int bi = 0;
    for (int it = 0; it < nt; ++it) {
        int pf = it + 2;
        if (pf < nt) stage(pf % 3, pf * 32);

        if (it < nt - 2)      asm volatile("s_waitcnt vmcnt(6)" ::: "memory");
        else if (it == nt - 2) asm volatile("s_waitcnt vmcnt(3)" ::: "memory");
        else                  asm volatile("s_waitcnt vmcnt(0)" ::: "memory");
        __builtin_amdgcn_s_barrier();          // all waves' tile-it loads landed
        asm volatile("" ::: "memory");

        s16x8 af[4], bfr[4];
#pragma unroll
        for (int i = 0; i < 4; ++i)
            af[i] = *(const s16x8*)&As[bi][(wm * 64 + i * 16 + l15) * 32 + ((quad ^ rsw) * 8)];
#pragma unroll
        for (int j = 0; j < 4; ++j)
            bfr[j] = *(const s16x8*)&Bs[bi][(wn * 64 + j * 16 + l15) * 32 + ((quad ^ rsw) * 8)];
#pragma unroll
        for (int i = 0; i < 4; ++i)
#pragma unroll
            for (int j = 0; j < 4; ++j)
                acc[i][j] = __builtin_amdgcn_mfma_f32_16x16x32_bf16(
                    af[i], bfr[j], acc[i][j], 0, 0, 0);

        asm volatile("" ::: "memory");
        __builtin_amdgcn_s_barrier();          // reads of buf bi done -> reusable
        asm volatile("" ::: "memory");
        bi = (bi + 1 == 3) ? 0 : bi + 1;
    }

    float colS[4] = {0.f, 0.f, 0.f, 0.f};
    float colQ[4] = {0.f, 0.f, 0.f, 0.f};
#pragma unroll
    for (int i = 0; i < 4; ++i)
#pragma unroll
        for (int j = 0; j < 4; ++j)
#pragma unroll
            for (int r = 0; r < 4; ++r) {
                int m = row0 + wm * 64 + i * 16 + quad * 4 + r;
                int nn = wn * 64 + j * 16 + l15;
                ushort_t cv = f2b(acc[i][j][r]);
                C[(size_t)m * H_ + nn] = cv;
                float v = b2f(cv);
                colS[j] += v;
                colQ[j] += v * v;
            }
    // reduce over quad (lane bits 4,5)
#pragma unroll
    for (int j = 0; j < 4; ++j) {
        colS[j] += __shfl_xor(colS[j], 16);
        colS[j] += __shfl_xor(colS[j], 32);
        colQ[j] += __shfl_xor(colQ[j], 16);
        colQ[j] += __shfl_xor(colQ[j], 32);
    }
    // block-level reduce via LDS (As is dead after the final barrier)
    float* ps = (float*)&As[0][0];   // [2][256]
    float* pq = ps + 512;            // [2][256]
    if (quad == 0) {
#pragma unroll
        for (int j = 0; j < 4; ++j) {
            int nn = wn * 64 + j * 16 + l15;
            ps[wm * 256 + nn] = colS[j];
            pq[wm * 256 + nn] = colQ[j];
        }
    }
    __syncthreads();
    if (t < 256) {
        float s = ps[t] + ps[256 + t];
        float q = pq[t] + pq[256 + t];
        int sh = (blockIdx.x & 7) * 256 + t;   // 8 shadow copies
        atomicAdd(&sumP[sh], s);
        atomicAdd(&sqP[sh], q);
    }
    // last-block BN-coef: syncthreads drains this block's atomics (vmcnt(0)
    // before s_barrier), so counter==gridDim implies all shadow adds landed.
    __syncthreads();
    if (t == 0)
        lastFlag = (atomicAdd(cnt, 1u) == (uint_t)(gridDim.x - 1)) ? 1u : 0u;
    __syncthreads();
    if (lastFlag != 0u && t < 256) {
        float s = 0.f, q = 0.f;
#pragma unroll
        for (int k = 0; k < 8; ++k) {
            s += atomicAdd(&sumP[k * 256 + t], 0.0f);   // coherent read path
            q += atomicAdd(&sqP[k * 256 + t], 0.0f);
        }
        float mean = s * (1.0f / P_);
        float var  = q * (1.0f / P_) - mean * mean;
        float ai = g[t] * rsqrtf(var + 1e-5f);
        a[t] = ai;
        c[t] = bt[t] - mean * ai;
    }
}

// BN + ReLU elementwise: x1 (P,256) bf16 -> h1 bf16, one uint4 (8 elems)/thread
__global__ __launch_bounds__(256) void bnrelu_k(
    const uint4* __restrict__ x, const float* __restrict__ a,
    const float* __restrict__ c, uint4* __restrict__ h) {
    size_t i = (size_t)blockIdx.x * 256 + threadIdx.x;   // 2,097,152 uint4s
    uint4 v = x[i];
    int chb = (int)((i * 8) & 255);
    const ushort_t* pv = (const ushort_t*)&v;
    uint4 o; ushort_t* po = (ushort_t*)&o;
    for (int j = 0; j < 8; ++j) {
        float f = b2f(pv[j]);
        f = a[chb + j] * f + c[chb + j];
        po[j] = f2b(fmaxf(f, 0.0f));
    }
    h[i] = o;
}

// BN + ReLU + transpose: x2 (P,256) bf16 -> out (B,256,N) f32, 64x64 tiles
__global__ __launch_bounds__(256) void final_k(
    const ushort_t* __restrict__ x2, const float* __restrict__ a,
    const float* __restrict__ c, float* __restrict__ out) {
    __shared__ float tile[64][65];
    int n0 = blockIdx.x * 64, c0 = blockIdx.y * 64, b = blockIdx.z;
    int t = threadIdx.x;
    {
        int cl = t & 63, pb = (t >> 6) * 16;
        float av = a[c0 + cl], cv = c[c0 + cl];
        for (int i = 0; i < 16; ++i) {
            float v = b2f(x2[((size_t)b * N_ + n0 + pb + i) * H_ + c0 + cl]);
            tile[cl][pb + i] = fmaxf(av * v + cv, 0.0f);
        }
    }
    __syncthreads();
    {
        int nl = t & 63, cb = (t >> 6) * 16;
        for (int i = 0; i < 16; ++i)
            out[((size_t)b * H_ + c0 + cb + i) * N_ + n0 + nl] = tile[cb + i][nl];
    }
}

// ---------------------------------------------------------------------------
extern "C" void kernel_launch(void* const* d_in, const int* in_sizes, int n_in,
                              void* d_out, int out_size, void* d_ws, size_t ws_size,
                              hipStream_t stream) {
    const float* unknown = (const float*)d_in[0];
    const float* known   = (const float*)d_in[1];
    const float* uf      = (const float*)d_in[2];
    const float* kf      = (const float*)d_in[3];
    const float* w1      = (const float*)d_in[4];
    const float* g1      = (const float*)d_in[5];
    const float* b1      = (const float*)d_in[6];
    const float* w2      = (const float*)d_in[7];
    const float* g2      = (const float*)d_in[8];
    const float* b2      = (const float*)d_in[9];
    float* out = (float*)d_out;

    char* ws = (char*)d_ws;
    // [0, 36K): shadow stats (4 x 8 x 256 f32) + a1,c1,a2,c2; [36K): counters
    float* fb    = (float*)ws;
    float* sum1P = fb;             // 2048
    float* sq1P  = fb + 2048;      // 2048
    float* sum2P = fb + 4096;      // 2048
    float* sq2P  = fb + 6144;      // 2048
    float* a1    = fb + 8192;      // 256
    float* c1    = fb + 8448;
    float* a2    = fb + 8704;
    float* c2    = fb + 8960;      // 9216 floats total
    uint_t* cnts = (uint_t*)(ws + 36864);   // 2 counters
    // [64K, 576K): converted weights
    ushort_t* w1b = (ushort_t*)(ws + 65536);                        // 384 KB
    ushort_t* w2b = (ushort_t*)(ws + 65536 + (size_t)H_ * K1_ * 2); // 128 KB
    const size_t MB = 1024 * 1024;
    // Lifetimes (stream-serialized):
    //   Acat [1,97): knn_k (all 768 cols) -> gemm1.
    //   kfT  [97,113): trans_k -> knn_k.
    //   x1   [97,129): gemm1 (kfT dead by then).
    //   h1   [1,33):  bnrelu (Acat dead) -> gemm2.
    //   x2   [33,65): gemm2 -> final.
    // Peak 129 MB.
    ushort_t* Acat = (ushort_t*)(ws + 1 * MB);      // 96 MB
    ushort_t* kfT  = (ushort_t*)(ws + 97 * MB);     // 16 MB
    ushort_t* x1   = (ushort_t*)(ws + 97 * MB);     // 32 MB
    ushort_t* h1   = (ushort_t*)(ws + 1 * MB);      // 32 MB
    ushort_t* x2   = (ushort_t*)(ws + 33 * MB);     // 32 MB

    initw_k<<<1025, 256, 0, stream>>>(w1, w2, w1b, w2b, fb, cnts);
    trans_k<<<2048, 256, 0, stream>>>(kf, kfT);
    knn_k<<<2048, 256, 0, stream>>>(unknown, known, kfT, uf, Acat);
    gemm_k<<<512, 512, 0, stream>>>(Acat, w1b, x1, K1_, sum1P, sq1P,
                                    g1, b1, a1, c1, &cnts[0]);
    bnrelu_k<<<8192, 256, 0, stream>>>((const uint4*)x1, a1, c1, (uint4*)h1);
    gemm_k<<<512, 512, 0, stream>>>(h1, w2b, x2, H_, sum2P, sq2P,
                                    g2, b2, a2, c2, &cnts[1]);
    final_k<<<dim3(64, 4, 16), 256, 0, stream>>>(x2, a2, c2, out);
}